// Round 4
// baseline (1675.547 us; speedup 1.0000x reference)
//
#include <hip/hip_runtime.h>
#include <stdint.h>

// ---------------------------------------------------------------------------
// ThermalLatticeSampler2D — round 4: packed-uint32 fused sweep, integer
// Metropolis thresholds, 64-row strips, energy fused into PT sweeps.
//
// Bit-exact jax.random (threefry2x32, partitionable mode) — validated R2/R3.
// State: int8 +-1, double-buffered in d_out bytes [0,N) / [N,2N).
// After 16 sweeps state is in buf0; staged in-place int8->fp32 expansion
// (validated R3) fills d_out[0,N) floats; energies -> d_out tail.
// ---------------------------------------------------------------------------

#define BB 32
#define CC 16
#define PLANE 65536                    // 256*256 bytes per (b,c) plane
#define NSITE (BB * CC * PLANE)        // 33554432
#define NPAIR ((BB - 1) * CC)          // 496
#define HSTRIP 64                      // rows finalized per block
#define ROWS_LD 69                     // rows loaded (halo: 2 top, 3 bottom)

// Threefry-2x32, 20 rounds (matches jax._src.prng.threefry2x32 exactly).
__host__ __device__ __forceinline__ void tf2x32(uint32_t k0, uint32_t k1,
                                                uint32_t c0, uint32_t c1,
                                                uint32_t& o0, uint32_t& o1) {
  uint32_t ks2 = k0 ^ k1 ^ 0x1BD11BDAu;
  uint32_t x0 = c0 + k0;
  uint32_t x1 = c1 + k1;
#define TF_ROT(r) { x0 += x1; x1 = (x1 << (r)) | (x1 >> (32 - (r))); x1 ^= x0; }
  TF_ROT(13) TF_ROT(15) TF_ROT(26) TF_ROT(6)
  x0 += k1;  x1 += ks2 + 1u;
  TF_ROT(17) TF_ROT(29) TF_ROT(16) TF_ROT(24)
  x0 += ks2; x1 += k0 + 2u;
  TF_ROT(13) TF_ROT(15) TF_ROT(26) TF_ROT(6)
  x0 += k0;  x1 += k1 + 3u;
  TF_ROT(17) TF_ROT(29) TF_ROT(16) TF_ROT(24)
  x0 += k1;  x1 += ks2 + 4u;
  TF_ROT(13) TF_ROT(15) TF_ROT(26) TF_ROT(6)
  x0 += ks2; x1 += k0 + 5u;
#undef TF_ROT
  o0 = x0; o1 = x1;
}

__device__ __forceinline__ float u01(uint32_t bits) {
  return __uint_as_float((bits >> 9) | 0x3f800000u) - 1.0f;
}

// ---- init: int32 {0,1} -> int8 {-1,+1} ------------------------------------
__global__ __launch_bounds__(256) void init8_k(const int* __restrict__ spins,
                                               uint8_t* __restrict__ s) {
  int i = blockIdx.x * 256 + threadIdx.x;          // over NSITE/4
  int4 v = ((const int4*)spins)[i];
  uint32_t o = ((uint32_t)(uint8_t)(int8_t)(2 * v.x - 1))
             | ((uint32_t)(uint8_t)(int8_t)(2 * v.y - 1) << 8)
             | ((uint32_t)(uint8_t)(int8_t)(2 * v.z - 1) << 16)
             | ((uint32_t)(uint8_t)(int8_t)(2 * v.w - 1) << 24);
  ((uint32_t*)s)[i] = o;
}

// ---- integer Metropolis thresholds: M = ceil(exp(-dE/T) * 2^23) -----------
// u < th  <=>  ((h0^h1)>>9) < M   (u = n*2^-23 exactly; proof in journal)
__global__ void prep_k(const float* __restrict__ T,
                       uint32_t* __restrict__ M4, uint32_t* __restrict__ M8) {
  int b = threadIdx.x;
  if (b < BB) {
    float t = T[b];
    float th4 = (float)exp((double)((-4.0f) / t));   // correctly-rounded f32
    float th8 = (float)exp((double)((-8.0f) / t));
    M4[b] = (uint32_t)ceil((double)th4 * 8388608.0);
    M8[b] = (uint32_t)ceil((double)th8 * 8388608.0);
  }
}

// ---- packed row update: one wave-row, 2 active-color sites per lane -------
__device__ __forceinline__ void process_row(uint32_t* tile32, int j, int y0,
                                            int lane, uint32_t bcbase,
                                            int color, uint32_t k0, uint32_t k1,
                                            uint32_t M4b, uint32_t M8b) {
  int gy = (y0 - 2 + j) & 255;
  uint32_t rowkey = bcbase + ((uint32_t)gy << 8) + (uint32_t)(lane << 2);
  int base = j * 64 + lane;
  uint32_t cur = tile32[base];
  uint32_t up  = tile32[base - 64];
  uint32_t dn  = tile32[base + 64];
  uint32_t pw  = tile32[j * 64 + ((lane + 63) & 63)];
  uint32_t nw  = tile32[j * 64 + ((lane + 1) & 63)];
  uint32_t lft = (cur << 8) | (pw >> 24);
  uint32_t rgt = (cur >> 8) | (nw << 24);
  // per-byte count of -1 neighbors (bit1 distinguishes 0x01 / 0xFF)
  uint32_t kd = ((up >> 1) & 0x01010101u) + ((dn >> 1) & 0x01010101u)
              + ((lft >> 1) & 0x01010101u) + ((rgt >> 1) & 0x01010101u);
  int p = (gy + color) & 1;                 // parity of active x in this word
  uint32_t flip = 0;
#pragma unroll
  for (int sIt = 0; sIt < 2; ++sIt) {
    int i = p + 2 * sIt;
    uint32_t kdi = (kd >> (8 * i)) & 0xFFu;
    uint32_t si  = (cur >> (8 * i + 1)) & 1u;
    uint32_t m   = si ? (4u - kdi) : kdi;   // # antiparallel neighbors
    bool accept = true;                     // m>=2 -> dE<=0 -> always flip
    if (m < 2u) {
      uint32_t h0, h1;
      tf2x32(k0, k1, 0u, rowkey + (uint32_t)i, h0, h1);
      uint32_t n = (h0 ^ h1) >> 9;
      accept = n < (m == 1u ? M4b : M8b);
    }
    if (accept) flip |= (0xFEu << (8 * i)); // 0x01 ^ 0xFE = 0xFF and v.v.
  }
  tile32[base] = cur ^ flip;
}

// ---- fused sweep: color0 + color1 (+ optional exact energy partials) ------
__global__ __launch_bounds__(256) void sweep_k(
    const uint8_t* __restrict__ src, uint8_t* __restrict__ dst,
    const uint32_t* __restrict__ M4, const uint32_t* __restrict__ M8,
    uint32_t kA0, uint32_t kA1, uint32_t kB0, uint32_t kB1,
    int t, const int* __restrict__ nsw, float* __restrict__ Estrip, int doE) {
  __shared__ __align__(16) uint32_t tile32[ROWS_LD * 64];
  __shared__ int red[4];
  int tid   = threadIdx.x;
  int bc    = blockIdx.x >> 2;              // plane b*16+c
  int strip = blockIdx.x & 3;
  int y0    = strip << 6;
  int b     = bc >> 4;
  uint32_t bcbase = (uint32_t)bc << 16;
  const uint8_t* sp = src + ((size_t)bc << 16);
  uint8_t*       dp = dst + ((size_t)bc << 16);
  bool active = (t < *nsw);
  uint32_t M4b = M4[b], M8b = M8[b];

  // load 69 rows = 1104 uint4
  for (int it = 0; it < 5; ++it) {
    int i = it * 256 + tid;
    if (i < ROWS_LD * 16) {
      int gy = (y0 - 2 + (i >> 4)) & 255;
      ((uint4*)tile32)[i] = *(const uint4*)(sp + (gy << 8) + ((i & 15) << 4));
    }
  }
  __syncthreads();

  int w = tid >> 6, lane = tid & 63;

  if (active) {                              // uniform
    for (int j = 1 + w; j < 68; j += 4)      // color 0: rows y0-1 .. y0+65
      process_row(tile32, j, y0, lane, bcbase, 0, kA0, kA1, M4b, M8b);
  }
  __syncthreads();
  if (active) {
    for (int j = 2 + w; j < 67; j += 4)      // color 1: rows y0 .. y0+64
      process_row(tile32, j, y0, lane, bcbase, 1, kB0, kB1, M4b, M8b);
  }
  __syncthreads();

  // store final rows j in [2,66) -> dst rows [y0, y0+64)  (1024 uint4)
  for (int it = 0; it < 4; ++it) {
    int i = it * 256 + tid;
    int gy = y0 + (i >> 4);
    *(uint4*)(dp + (gy << 8) + ((i & 15) << 4)) = ((uint4*)tile32)[32 + i];
  }

  if (doE) {                                 // uniform
    // exact integer energy partial over rows [y0, y0+64): sum s*(right+down)
    int acc = 0;
#pragma unroll 4
    for (int q = 0; q < 16; ++q) {
      int j = 2 + w + 4 * q;                 // stride-1 lane access: no conflicts
      uint32_t cur = tile32[j * 64 + lane];
      uint32_t nxt = tile32[j * 64 + ((lane + 1) & 63)];
      uint32_t dwn = tile32[j * 64 + 64 + lane];
      uint32_t rsh = (cur >> 8) | (nxt << 24);
      int d = __builtin_popcount((cur ^ rsh) & 0x02020202u)
            + __builtin_popcount((cur ^ dwn) & 0x02020202u);
      acc += 8 - 2 * d;
    }
    for (int off = 32; off > 0; off >>= 1) acc += __shfl_down(acc, off, 64);
    if (lane == 0) red[w] = acc;
    __syncthreads();
    if (tid == 0)
      Estrip[blockIdx.x] = (float)(red[0] + red[1] + red[2] + red[3]);
  }
}

// ---- PT decision: sum strip partials -> plane E; pair accept --------------
__global__ void pt_decide_k(const float* __restrict__ Estrip,
                            const float* __restrict__ T,
                            float* __restrict__ Eplane,
                            uint32_t k0, uint32_t k1, int pair_parity,
                            int* __restrict__ accf, int t,
                            const int* __restrict__ nsw) {
  int tid = threadIdx.x;                     // 512 threads
  float e = Estrip[tid * 4] + Estrip[tid * 4 + 1]
          + Estrip[tid * 4 + 2] + Estrip[tid * 4 + 3];
  Eplane[tid] = -e;                          // exact integers in fp32
  __syncthreads();
  if (tid < NPAIR) {
    if (t >= *nsw) { accf[tid] = 0; return; }
    int b = tid >> 4;
    float d = (1.0f / T[b] - 1.0f / T[b + 1]) * (Eplane[tid] - Eplane[tid + 16]);
    uint32_t h0, h1;
    tf2x32(k0, k1, 0u, (uint32_t)tid, h0, h1);
    float u = u01(h0 ^ h1);
    float th = (float)exp((double)d);
    accf[tid] = (u < th) && ((b & 1) == pair_parity);
  }
}

// ---- apply accepted swaps: exchange 64KB planes ---------------------------
__global__ __launch_bounds__(256) void pt_swap8_k(uint8_t* __restrict__ s,
                                                  const int* __restrict__ accf) {
  int pc = blockIdx.x;
  if (!accf[pc]) return;
  uint4* p0 = (uint4*)(s + ((size_t)pc << 16));
  uint4* p1 = p0 + (CC * PLANE / 16);        // plane (b+1, c)
  for (int j = threadIdx.x; j < PLANE / 16; j += 256) {
    uint4 a0 = p0[j], a1 = p1[j];
    p0[j] = a1; p1[j] = a0;
  }
}

// ---- final energies = PT(t=15) permutation of plane energies --------------
__global__ void final_eout_k(const float* __restrict__ Eplane,
                             const int* __restrict__ accf,
                             float* __restrict__ Eout) {
  int tid = threadIdx.x;                     // 512
  int b = tid >> 4;
  float e = Eplane[tid];
  if (b < 31 && accf[tid])      e = Eplane[tid + 16];
  if (b > 0  && accf[tid - 16]) e = Eplane[tid - 16];
  Eout[tid] = e;
}

// ---- staged in-place int8 -> fp32 expansion (validated R3) ----------------
__global__ __launch_bounds__(256) void expand_k(const int8_t* __restrict__ st,
                                                float* __restrict__ out,
                                                int lo, int cnt4) {
  int i = blockIdx.x * 256 + threadIdx.x;
  if (i >= cnt4) return;
  uint32_t v = *(const uint32_t*)(st + lo + 4 * i);
  float4 o;
  o.x = (float)(int8_t)(v);
  o.y = (float)(int8_t)(v >> 8);
  o.z = (float)(int8_t)(v >> 16);
  o.w = (float)(int8_t)(v >> 24);
  ((float4*)out)[(lo >> 2) + i] = o;
}

__global__ __launch_bounds__(256) void expand_head_k(const int8_t* __restrict__ st,
                                                     float* __restrict__ out) {
  uint32_t r[8];
  int t = threadIdx.x;
  for (int u = 0; u < 8; ++u) r[u] = *(const uint32_t*)(st + t * 32 + 4 * u);
  __syncthreads();
  for (int u = 0; u < 8; ++u) {
    uint32_t v = r[u];
    float4 o;
    o.x = (float)(int8_t)(v);
    o.y = (float)(int8_t)(v >> 8);
    o.z = (float)(int8_t)(v >> 16);
    o.w = (float)(int8_t)(v >> 24);
    ((float4*)out)[t * 8 + u] = o;
  }
}

extern "C" void kernel_launch(void* const* d_in, const int* in_sizes, int n_in,
                              void* d_out, int out_size, void* d_ws, size_t ws_size,
                              hipStream_t stream) {
  (void)in_sizes; (void)n_in; (void)out_size; (void)ws_size;
  const float* T    = (const float*)d_in[0];
  const int*  spins = (const int*)d_in[1];
  const int*  nsw   = (const int*)d_in[2];

  uint8_t* buf0 = (uint8_t*)d_out;               // bytes [0, N)
  uint8_t* buf1 = buf0 + NSITE;                  // bytes [N, 2N)
  float*   outf = (float*)d_out;
  float*   Eout = outf + NSITE;                  // 512 floats after spin region

  float*    Estrip = (float*)d_ws;               // 2048
  float*    Eplane = Estrip + 2048;              // 512
  uint32_t* M4     = (uint32_t*)(Eplane + 512);  // 32
  uint32_t* M8     = M4 + BB;                    // 32
  int*      accf   = (int*)(M8 + BB);            // 496

  init8_k<<<NSITE / 1024, 256, 0, stream>>>(spins, buf0);
  prep_k<<<1, 64, 0, stream>>>(T, M4, M8);

  for (int t = 0; t < 16; ++t) {
    uint32_t kb0, kb1;
    tf2x32(0u, 42u, 0u, (uint32_t)t, kb0, kb1);  // fold_in(key(42), t)
    uint32_t k1a, k1b, k2a, k2b, k3a, k3b;
    tf2x32(kb0, kb1, 0u, 0u, k1a, k1b);
    tf2x32(kb0, kb1, 0u, 1u, k2a, k2b);
    tf2x32(kb0, kb1, 0u, 2u, k3a, k3b);

    uint8_t* src = (t & 1) ? buf1 : buf0;
    uint8_t* dst = (t & 1) ? buf0 : buf1;
    int doE = ((t & 3) == 3);
    sweep_k<<<BB * CC * 4, 256, 0, stream>>>(src, dst, M4, M8,
                                             k1a, k1b, k2a, k2b, t, nsw,
                                             Estrip, doE);
    if (doE) {                                   // dst == buf0 (t odd)
      pt_decide_k<<<1, 512, 0, stream>>>(Estrip, T, Eplane, k3a, k3b,
                                         (t >> 2) & 1, accf, t, nsw);
      pt_swap8_k<<<NPAIR, 256, 0, stream>>>(buf0, accf);
    }
  }

  final_eout_k<<<1, 512, 0, stream>>>(Eplane, accf, Eout);

  // staged in-place expansion (each stage reads [lo,4lo), writes [4lo,16lo))
  for (int lo = NSITE / 4; lo >= 8192; lo >>= 2) {
    int cnt4 = (lo * 3) / 4;
    expand_k<<<(cnt4 + 255) / 256, 256, 0, stream>>>((int8_t*)buf0, outf, lo, cnt4);
  }
  expand_head_k<<<1, 256, 0, stream>>>((int8_t*)buf0, outf);
}

// Round 5
// 1519.748 us; speedup vs baseline: 1.1025x; 1.1025x over previous
//
#include <hip/hip_runtime.h>
#include <stdint.h>

// ---------------------------------------------------------------------------
// ThermalLatticeSampler2D — round 5: whole-plane-in-LDS persistent sweeps.
// One 1024-thread block per (b,c) plane; 64KB plane in LDS; 4 sweeps per
// kernel launch; PT swap kernels between. 512 blocks = 2/CU = 32 waves/CU.
//
// Bit-exact jax.random (threefry2x32, partitionable mode) — validated R2-R4.
// State: int8 +-1 in d_out bytes [0,N), N=33554432 (in-place, no dbuf).
// After 16 sweeps: staged in-place int8->fp32 expansion (validated R3/R4)
// fills d_out[0,N) floats; energies -> d_out tail (512 floats).
// ---------------------------------------------------------------------------

#define BB 32
#define CC 16
#define PLANE 65536                    // bytes per (b,c) plane
#define NSITE (BB * CC * PLANE)        // 33554432
#define NPAIR ((BB - 1) * CC)          // 496

// Threefry-2x32, 20 rounds (matches jax._src.prng.threefry2x32 exactly).
__host__ __device__ __forceinline__ void tf2x32(uint32_t k0, uint32_t k1,
                                                uint32_t c0, uint32_t c1,
                                                uint32_t& o0, uint32_t& o1) {
  uint32_t ks2 = k0 ^ k1 ^ 0x1BD11BDAu;
  uint32_t x0 = c0 + k0;
  uint32_t x1 = c1 + k1;
#define TF_ROT(r) { x0 += x1; x1 = (x1 << (r)) | (x1 >> (32 - (r))); x1 ^= x0; }
  TF_ROT(13) TF_ROT(15) TF_ROT(26) TF_ROT(6)
  x0 += k1;  x1 += ks2 + 1u;
  TF_ROT(17) TF_ROT(29) TF_ROT(16) TF_ROT(24)
  x0 += ks2; x1 += k0 + 2u;
  TF_ROT(13) TF_ROT(15) TF_ROT(26) TF_ROT(6)
  x0 += k0;  x1 += k1 + 3u;
  TF_ROT(17) TF_ROT(29) TF_ROT(16) TF_ROT(24)
  x0 += k1;  x1 += ks2 + 4u;
  TF_ROT(13) TF_ROT(15) TF_ROT(26) TF_ROT(6)
  x0 += ks2; x1 += k0 + 5u;
#undef TF_ROT
  o0 = x0; o1 = x1;
}

__device__ __forceinline__ float u01(uint32_t bits) {
  return __uint_as_float((bits >> 9) | 0x3f800000u) - 1.0f;
}

// ---- init: int32 {0,1} -> int8 {-1,+1} ------------------------------------
__global__ __launch_bounds__(256) void init8_k(const int* __restrict__ spins,
                                               uint8_t* __restrict__ s) {
  int i = blockIdx.x * 256 + threadIdx.x;          // over NSITE/4
  int4 v = ((const int4*)spins)[i];
  uint32_t o = ((uint32_t)(uint8_t)(int8_t)(2 * v.x - 1))
             | ((uint32_t)(uint8_t)(int8_t)(2 * v.y - 1) << 8)
             | ((uint32_t)(uint8_t)(int8_t)(2 * v.z - 1) << 16)
             | ((uint32_t)(uint8_t)(int8_t)(2 * v.w - 1) << 24);
  ((uint32_t*)s)[i] = o;
}

// ---- integer Metropolis thresholds: M = ceil(exp(-dE/T) * 2^23) -----------
// u < th  <=>  ((h0^h1)>>9) < M   (u = n*2^-23 exactly)
__global__ void prep_k(const float* __restrict__ T,
                       uint32_t* __restrict__ M4, uint32_t* __restrict__ M8) {
  int b = threadIdx.x;
  if (b < BB) {
    float t = T[b];
    float th4 = (float)exp((double)((-4.0f) / t));   // correctly-rounded f32
    float th8 = (float)exp((double)((-8.0f) / t));
    M4[b] = (uint32_t)ceil((double)th4 * 8388608.0);
    M8[b] = (uint32_t)ceil((double)th8 * 8388608.0);
  }
}

// ---- one color pass over the whole plane (in LDS) -------------------------
// Word (row j, lane) owned by thread (w = j%16, lane). Readers consume only
// opposite-color bytes of neighbor words -> race-free (LDS b32 is atomic).
__device__ __forceinline__ void do_color(uint32_t* __restrict__ tile,
    int w, int lane, uint32_t bcbase, int color,
    uint32_t k0, uint32_t k1, uint32_t M4b, uint32_t M8b) {
  int lm = (lane + 63) & 63, lp = (lane + 1) & 63;
#pragma unroll 4
  for (int j = w; j < 256; j += 16) {
    int rb = j << 6;
    uint32_t cur = tile[rb + lane];
    uint32_t up  = tile[(((j + 255) & 255) << 6) + lane];
    uint32_t dn  = tile[(((j + 1) & 255) << 6) + lane];
    uint32_t pw  = tile[rb + lm];
    uint32_t nw  = tile[rb + lp];
    uint32_t lft = (cur << 8) | (pw >> 24);
    uint32_t rgt = (cur >> 8) | (nw << 24);
    // per-byte count of -1 neighbors (bit1 distinguishes 0x01 / 0xFF)
    uint32_t kd = ((up >> 1) & 0x01010101u) + ((dn >> 1) & 0x01010101u)
                + ((lft >> 1) & 0x01010101u) + ((rgt >> 1) & 0x01010101u);
    int p = (j + color) & 1;                 // parity of active bytes
    uint32_t rowkey = bcbase + ((uint32_t)j << 8)
                    + (uint32_t)(lane << 2) + (uint32_t)p;
    uint32_t flip = 0;
    {                                        // site 0: byte p
      uint32_t kdi = (kd >> (8 * p)) & 0xFFu;
      uint32_t si  = (cur >> (8 * p + 1)) & 1u;
      uint32_t m   = si ? (4u - kdi) : kdi;  // # antiparallel; dE = 8-4m
      bool a = true;                         // m>=2 -> dE<=0 -> flip
      if (m < 2u) {
        uint32_t h0, h1;
        tf2x32(k0, k1, 0u, rowkey, h0, h1);
        a = ((h0 ^ h1) >> 9) < (m ? M4b : M8b);
      }
      if (a) flip |= 0xFEu << (8 * p);       // 0x01^0xFE=0xFF and v.v.
    }
    {                                        // site 1: byte p+2
      uint32_t kdi = (kd >> (8 * p + 16)) & 0xFFu;
      uint32_t si  = (cur >> (8 * p + 17)) & 1u;
      uint32_t m   = si ? (4u - kdi) : kdi;
      bool a = true;
      if (m < 2u) {
        uint32_t h0, h1;
        tf2x32(k0, k1, 0u, rowkey + 2u, h0, h1);
        a = ((h0 ^ h1) >> 9) < (m ? M4b : M8b);
      }
      if (a) flip |= 0xFE0000u << (8 * p);
    }
    tile[rb + lane] = cur ^ flip;
  }
}

// ---- 4 sweeps on one plane, fully LDS-resident; exact energy at end -------
__global__ __launch_bounds__(1024) void sweep4_k(
    uint8_t* __restrict__ sg,
    const uint32_t* __restrict__ M4, const uint32_t* __restrict__ M8,
    uint4 kS0, uint4 kS1, uint4 kS2, uint4 kS3,
    int tbase, const int* __restrict__ nsw, float* __restrict__ Eplane) {
  __shared__ uint32_t tile[16384];           // exactly 64 KB
  int tid = threadIdx.x;
  int bc  = blockIdx.x;
  int b   = bc >> 4;
  uint32_t bcbase = (uint32_t)bc << 16;
  uint32_t* gp = (uint32_t*)(sg + ((size_t)bc << 16));
  uint32_t M4b = M4[b], M8b = M8[b];
  int nswv = *nsw;

  for (int i = tid; i < 4096; i += 1024)     // load plane (4 uint4/thread)
    ((uint4*)tile)[i] = ((const uint4*)gp)[i];
  __syncthreads();

  int w = tid >> 6, lane = tid & 63;
  uint4 keys[4] = {kS0, kS1, kS2, kS3};
#pragma unroll
  for (int ss = 0; ss < 4; ++ss) {
    if (tbase + ss < nswv) {                 // uniform
      do_color(tile, w, lane, bcbase, 0, keys[ss].x, keys[ss].y, M4b, M8b);
      __syncthreads();
      do_color(tile, w, lane, bcbase, 1, keys[ss].z, keys[ss].w, M4b, M8b);
      __syncthreads();
    }
  }

  // exact integer energy partial: sum s*(right+down) over owned words
  int acc = 0;
  for (int j = w; j < 256; j += 16) {
    uint32_t cur = tile[(j << 6) + lane];
    uint32_t nxt = tile[(j << 6) + ((lane + 1) & 63)];
    uint32_t dwn = tile[(((j + 1) & 255) << 6) + lane];
    uint32_t rsh = (cur >> 8) | (nxt << 24);
    int d = __builtin_popcount((cur ^ rsh) & 0x02020202u)
          + __builtin_popcount((cur ^ dwn) & 0x02020202u);
    acc += 8 - 2 * d;
  }

  for (int i = tid; i < 4096; i += 1024)     // store plane back
    ((uint4*)gp)[i] = ((uint4*)tile)[i];
  __syncthreads();                           // all tile reads done

  for (int off = 32; off > 0; off >>= 1) acc += __shfl_down(acc, off, 64);
  if (lane == 0) tile[w] = (uint32_t)acc;    // reuse tile[0..15]
  __syncthreads();
  if (tid == 0) {
    int tot = 0;
    for (int i = 0; i < 16; ++i) tot += (int)tile[i];
    Eplane[bc] = -(float)tot;
  }
}

// ---- PT swap decision ------------------------------------------------------
__global__ void pt_decide_k(const float* __restrict__ Eplane,
                            const float* __restrict__ T,
                            uint32_t k0, uint32_t k1, int pair_parity,
                            int* __restrict__ accf, int t,
                            const int* __restrict__ nsw) {
  int tid = threadIdx.x;                     // 512 threads, first 496 used
  if (tid >= NPAIR) return;
  if (t >= *nsw) { accf[tid] = 0; return; }
  int b = tid >> 4;
  float d = (1.0f / T[b] - 1.0f / T[b + 1]) * (Eplane[tid] - Eplane[tid + 16]);
  uint32_t h0, h1;
  tf2x32(k0, k1, 0u, (uint32_t)tid, h0, h1);
  float u = u01(h0 ^ h1);
  float th = (float)exp((double)d);
  accf[tid] = (u < th) && ((b & 1) == pair_parity);
}

// ---- apply accepted swaps: exchange 64KB planes ---------------------------
__global__ __launch_bounds__(256) void pt_swap8_k(uint8_t* __restrict__ s,
                                                  const int* __restrict__ accf) {
  int pc = blockIdx.x;
  if (!accf[pc]) return;
  uint4* p0 = (uint4*)(s + ((size_t)pc << 16));
  uint4* p1 = p0 + (CC * PLANE / 16);        // plane (b+1, c)
  for (int j = threadIdx.x; j < PLANE / 16; j += 256) {
    uint4 a0 = p0[j], a1 = p1[j];
    p0[j] = a1; p1[j] = a0;
  }
}

// ---- final energies = PT(t=15) permutation of plane energies --------------
__global__ void final_eout_k(const float* __restrict__ Eplane,
                             const int* __restrict__ accf,
                             float* __restrict__ Eout) {
  int tid = threadIdx.x;                     // 512
  int b = tid >> 4;
  float e = Eplane[tid];
  if (b < 31 && accf[tid])      e = Eplane[tid + 16];
  if (b > 0  && accf[tid - 16]) e = Eplane[tid - 16];
  Eout[tid] = e;
}

// ---- staged in-place int8 -> fp32 expansion (validated R3/R4) -------------
__global__ __launch_bounds__(256) void expand_k(const int8_t* __restrict__ st,
                                                float* __restrict__ out,
                                                int lo, int cnt4) {
  int i = blockIdx.x * 256 + threadIdx.x;
  if (i >= cnt4) return;
  uint32_t v = *(const uint32_t*)(st + lo + 4 * i);
  float4 o;
  o.x = (float)(int8_t)(v);
  o.y = (float)(int8_t)(v >> 8);
  o.z = (float)(int8_t)(v >> 16);
  o.w = (float)(int8_t)(v >> 24);
  ((float4*)out)[(lo >> 2) + i] = o;
}

__global__ __launch_bounds__(256) void expand_head_k(const int8_t* __restrict__ st,
                                                     float* __restrict__ out) {
  uint32_t r[8];
  int t = threadIdx.x;
  for (int u = 0; u < 8; ++u) r[u] = *(const uint32_t*)(st + t * 32 + 4 * u);
  __syncthreads();
  for (int u = 0; u < 8; ++u) {
    uint32_t v = r[u];
    float4 o;
    o.x = (float)(int8_t)(v);
    o.y = (float)(int8_t)(v >> 8);
    o.z = (float)(int8_t)(v >> 16);
    o.w = (float)(int8_t)(v >> 24);
    ((float4*)out)[t * 8 + u] = o;
  }
}

extern "C" void kernel_launch(void* const* d_in, const int* in_sizes, int n_in,
                              void* d_out, int out_size, void* d_ws, size_t ws_size,
                              hipStream_t stream) {
  (void)in_sizes; (void)n_in; (void)out_size; (void)ws_size;
  const float* T    = (const float*)d_in[0];
  const int*  spins = (const int*)d_in[1];
  const int*  nsw   = (const int*)d_in[2];

  uint8_t* buf0 = (uint8_t*)d_out;               // int8 state, in-place
  float*   outf = (float*)d_out;
  float*   Eout = outf + NSITE;                  // 512 floats after spins

  float*    Eplane = (float*)d_ws;               // 512
  uint32_t* M4     = (uint32_t*)(Eplane + 512);  // 32
  uint32_t* M8     = M4 + BB;                    // 32
  int*      accf   = (int*)(M8 + BB);            // 496

  init8_k<<<NSITE / 1024, 256, 0, stream>>>(spins, buf0);
  prep_k<<<1, 64, 0, stream>>>(T, M4, M8);

  for (int g = 0; g < 4; ++g) {
    uint4 kS[4];
    uint32_t k3a = 0, k3b = 0;
    for (int i = 0; i < 4; ++i) {
      int t = 4 * g + i;
      uint32_t kb0, kb1;
      tf2x32(0u, 42u, 0u, (uint32_t)t, kb0, kb1);     // fold_in(key(42), t)
      tf2x32(kb0, kb1, 0u, 0u, kS[i].x, kS[i].y);     // color-0 key
      tf2x32(kb0, kb1, 0u, 1u, kS[i].z, kS[i].w);     // color-1 key
      if (i == 3) tf2x32(kb0, kb1, 0u, 2u, k3a, k3b); // PT key
    }
    sweep4_k<<<BB * CC, 1024, 0, stream>>>(buf0, M4, M8,
                                           kS[0], kS[1], kS[2], kS[3],
                                           4 * g, nsw, Eplane);
    pt_decide_k<<<1, 512, 0, stream>>>(Eplane, T, k3a, k3b, g & 1,
                                       accf, 4 * g + 3, nsw);
    pt_swap8_k<<<NPAIR, 256, 0, stream>>>(buf0, accf);
  }

  final_eout_k<<<1, 512, 0, stream>>>(Eplane, accf, Eout);

  // staged in-place expansion (each stage reads [lo,4lo), writes floats there)
  for (int lo = NSITE / 4; lo >= 8192; lo >>= 2) {
    int cnt4 = (lo * 3) / 4;
    expand_k<<<(cnt4 + 255) / 256, 256, 0, stream>>>((int8_t*)buf0, outf, lo, cnt4);
  }
  expand_head_k<<<1, 256, 0, stream>>>((int8_t*)buf0, outf);
}

// Round 6
// 1464.227 us; speedup vs baseline: 1.1443x; 1.0379x over previous
//
#include <hip/hip_runtime.h>
#include <stdint.h>

// ---------------------------------------------------------------------------
// ThermalLatticeSampler2D — round 6: R5 structure (whole-plane-in-LDS, 4
// sweeps/launch) + instruction-count diet: 1-op rotates (alignbit), SALU
// scalarization of wave-uniform row math, hoisted hash counter base.
//
// Bit-exact jax.random (threefry2x32, partitionable mode) — validated R2-R5.
// State: int8 +-1 in d_out bytes [0,N), N=33554432 (in-place).
// After 16 sweeps: staged in-place int8->fp32 expansion fills d_out floats;
// energies -> d_out tail (512 floats).
// ---------------------------------------------------------------------------

#define BB 32
#define CC 16
#define PLANE 65536
#define NSITE (BB * CC * PLANE)        // 33554432
#define NPAIR ((BB - 1) * CC)          // 496

// Full threefry (used host-side for keys and in pt_decide).
__host__ __device__ __forceinline__ void tf2x32(uint32_t k0, uint32_t k1,
                                                uint32_t c0, uint32_t c1,
                                                uint32_t& o0, uint32_t& o1) {
  uint32_t ks2 = k0 ^ k1 ^ 0x1BD11BDAu;
  uint32_t x0 = c0 + k0;
  uint32_t x1 = c1 + k1;
#define TF_ROT(r) { x0 += x1; x1 = (x1 << (r)) | (x1 >> (32 - (r))); x1 ^= x0; }
  TF_ROT(13) TF_ROT(15) TF_ROT(26) TF_ROT(6)
  x0 += k1;  x1 += ks2 + 1u;
  TF_ROT(17) TF_ROT(29) TF_ROT(16) TF_ROT(24)
  x0 += ks2; x1 += k0 + 2u;
  TF_ROT(13) TF_ROT(15) TF_ROT(26) TF_ROT(6)
  x0 += k0;  x1 += k1 + 3u;
  TF_ROT(17) TF_ROT(29) TF_ROT(16) TF_ROT(24)
  x0 += k1;  x1 += ks2 + 4u;
  TF_ROT(13) TF_ROT(15) TF_ROT(26) TF_ROT(6)
  x0 += ks2; x1 += k0 + 5u;
#undef TF_ROT
  o0 = x0; o1 = x1;
}

// Device hash for c0==0, x1i = c1 + k1 precomputed. Returns o0 ^ o1.
// Rotates forced to v_alignbit via __builtin_rotateleft32.
__device__ __forceinline__ uint32_t tf_bits(uint32_t k0, uint32_t k1,
                                            uint32_t ks2, uint32_t x1i) {
  uint32_t x0 = k0, x1 = x1i;
#define R4(a,b,c,d) \
  x0 += x1; x1 = __builtin_rotateleft32(x1, (a)); x1 ^= x0; \
  x0 += x1; x1 = __builtin_rotateleft32(x1, (b)); x1 ^= x0; \
  x0 += x1; x1 = __builtin_rotateleft32(x1, (c)); x1 ^= x0; \
  x0 += x1; x1 = __builtin_rotateleft32(x1, (d)); x1 ^= x0;
  R4(13,15,26,6)  x0 += k1;  x1 += ks2 + 1u;
  R4(17,29,16,24) x0 += ks2; x1 += k0 + 2u;
  R4(13,15,26,6)  x0 += k0;  x1 += k1 + 3u;
  R4(17,29,16,24) x0 += k1;  x1 += ks2 + 4u;
  R4(13,15,26,6)  x0 += ks2; x1 += k0 + 5u;
#undef R4
  return x0 ^ x1;
}

__device__ __forceinline__ float u01(uint32_t bits) {
  return __uint_as_float((bits >> 9) | 0x3f800000u) - 1.0f;
}

// ---- init: int32 {0,1} -> int8 {-1,+1} ------------------------------------
__global__ __launch_bounds__(256) void init8_k(const int* __restrict__ spins,
                                               uint8_t* __restrict__ s) {
  int i = blockIdx.x * 256 + threadIdx.x;
  int4 v = ((const int4*)spins)[i];
  uint32_t o = ((uint32_t)(uint8_t)(int8_t)(2 * v.x - 1))
             | ((uint32_t)(uint8_t)(int8_t)(2 * v.y - 1) << 8)
             | ((uint32_t)(uint8_t)(int8_t)(2 * v.z - 1) << 16)
             | ((uint32_t)(uint8_t)(int8_t)(2 * v.w - 1) << 24);
  ((uint32_t*)s)[i] = o;
}

// ---- integer Metropolis thresholds: M = ceil(exp(-dE/T) * 2^23) -----------
__global__ void prep_k(const float* __restrict__ T,
                       uint32_t* __restrict__ M4, uint32_t* __restrict__ M8) {
  int b = threadIdx.x;
  if (b < BB) {
    float t = T[b];
    float th4 = (float)exp((double)((-4.0f) / t));
    float th8 = (float)exp((double)((-8.0f) / t));
    M4[b] = (uint32_t)ceil((double)th4 * 8388608.0);
    M8[b] = (uint32_t)ceil((double)th8 * 8388608.0);
  }
}

// ---- one color pass over the plane in LDS ---------------------------------
// w is wave-uniform (readfirstlane'd) -> all row math is SALU.
// vk = k1 + bcbase + (lane<<2) hoisted; per-hash counter init = 1 v_add.
__device__ __forceinline__ void do_color(uint32_t* __restrict__ tile,
    int w, int lane, int lm, int lp, uint32_t vk, int color,
    uint32_t k0, uint32_t k1, uint32_t ks2, uint32_t M4b, uint32_t M8b) {
#pragma unroll 4
  for (int it = 0; it < 16; ++it) {
    int j  = w + it * 16;                    // scalar
    int rb = j << 6;                          // scalar
    int ju = ((j + 255) & 255) << 6;          // scalar
    int jd = ((j + 1) & 255) << 6;            // scalar
    int p  = (j + color) & 1;                 // scalar
    uint32_t soff = (uint32_t)((j << 8) + p); // scalar

    uint32_t cur = tile[rb + lane];
    uint32_t up  = tile[ju + lane];
    uint32_t dn  = tile[jd + lane];
    uint32_t pw  = tile[rb + lm];
    uint32_t nw  = tile[rb + lp];
    uint32_t lft = __builtin_amdgcn_alignbit(cur, pw, 24); // (cur<<8)|(pw>>24)
    uint32_t rgt = __builtin_amdgcn_alignbit(nw, cur, 8);  // (cur>>8)|(nw<<24)
    // per-byte 2*(# of -1 neighbors): values 0..8, no cross-byte carry
    uint32_t kd2 = (up & 0x02020202u) + (dn & 0x02020202u)
                 + (lft & 0x02020202u) + (rgt & 0x02020202u);

    uint32_t flip = 0;
    {                                        // site A: byte p
      uint32_t kdi = (kd2 >> (8 * p)) & 0xFFu;
      uint32_t si  = (cur >> (8 * p + 1)) & 1u;
      uint32_t m2  = si ? (8u - kdi) : kdi;  // 2*(# antiparallel)
      bool a = true;                         // m2>=4 -> dE<=0 -> flip
      if (m2 < 4u) {
        uint32_t n = tf_bits(k0, k1, ks2, vk + soff) >> 9;
        a = n < (m2 == 2u ? M4b : M8b);
      }
      if (a) flip |= 0xFEu << (8 * p);
    }
    {                                        // site B: byte p+2
      uint32_t kdi = (kd2 >> (8 * p + 16)) & 0xFFu;
      uint32_t si  = (cur >> (8 * p + 17)) & 1u;
      uint32_t m2  = si ? (8u - kdi) : kdi;
      bool a = true;
      if (m2 < 4u) {
        uint32_t n = tf_bits(k0, k1, ks2, vk + soff + 2u) >> 9;
        a = n < (m2 == 2u ? M4b : M8b);
      }
      if (a) flip |= 0xFE0000u << (8 * p);
    }
    tile[rb + lane] = cur ^ flip;
  }
}

// ---- 4 sweeps on one plane, fully LDS-resident; exact energy at end -------
__global__ __launch_bounds__(1024) void sweep4_k(
    uint8_t* __restrict__ sg,
    const uint32_t* __restrict__ M4, const uint32_t* __restrict__ M8,
    uint4 kS0, uint4 kS1, uint4 kS2, uint4 kS3,
    int tbase, const int* __restrict__ nsw, float* __restrict__ Eplane) {
  __shared__ uint32_t tile[16384];           // exactly 64 KB
  int tid = threadIdx.x;
  int bc  = blockIdx.x;
  int b   = bc >> 4;
  uint32_t bcbase = (uint32_t)bc << 16;
  uint32_t* gp = (uint32_t*)(sg + ((size_t)bc << 16));
  uint32_t M4b = M4[b], M8b = M8[b];
  int nswv = *nsw;

  for (int i = tid; i < 4096; i += 1024)
    ((uint4*)tile)[i] = ((const uint4*)gp)[i];
  __syncthreads();

  int w    = __builtin_amdgcn_readfirstlane(tid >> 6);  // wave-uniform -> SALU
  int lane = tid & 63;
  int lm   = (lane + 63) & 63, lp = (lane + 1) & 63;

  uint4 keys[4] = {kS0, kS1, kS2, kS3};
#pragma unroll
  for (int ss = 0; ss < 4; ++ss) {
    if (tbase + ss < nswv) {                 // uniform
      uint32_t kA0 = keys[ss].x, kA1 = keys[ss].y;
      uint32_t kB0 = keys[ss].z, kB1 = keys[ss].w;
      uint32_t ksA = kA0 ^ kA1 ^ 0x1BD11BDAu;
      uint32_t ksB = kB0 ^ kB1 ^ 0x1BD11BDAu;
      uint32_t vkA = kA1 + bcbase + (uint32_t)(lane << 2);
      uint32_t vkB = kB1 + bcbase + (uint32_t)(lane << 2);
      do_color(tile, w, lane, lm, lp, vkA, 0, kA0, kA1, ksA, M4b, M8b);
      __syncthreads();
      do_color(tile, w, lane, lm, lp, vkB, 1, kB0, kB1, ksB, M4b, M8b);
      __syncthreads();
    }
  }

  // exact integer energy partial: sum s*(right+down) over owned words
  int acc = 0;
  for (int it = 0; it < 16; ++it) {
    int j = w + it * 16;
    uint32_t cur = tile[(j << 6) + lane];
    uint32_t nxt = tile[(j << 6) + lp];
    uint32_t dwn = tile[((((j + 1) & 255)) << 6) + lane];
    uint32_t rsh = (cur >> 8) | (nxt << 24);
    int d = __builtin_popcount((cur ^ rsh) & 0x02020202u)
          + __builtin_popcount((cur ^ dwn) & 0x02020202u);
    acc += 8 - 2 * d;
  }

  for (int i = tid; i < 4096; i += 1024)
    ((uint4*)gp)[i] = ((uint4*)tile)[i];
  __syncthreads();

  for (int off = 32; off > 0; off >>= 1) acc += __shfl_down(acc, off, 64);
  if (lane == 0) tile[w] = (uint32_t)acc;
  __syncthreads();
  if (tid == 0) {
    int tot = 0;
    for (int i = 0; i < 16; ++i) tot += (int)tile[i];
    Eplane[bc] = -(float)tot;
  }
}

// ---- PT swap decision ------------------------------------------------------
__global__ void pt_decide_k(const float* __restrict__ Eplane,
                            const float* __restrict__ T,
                            uint32_t k0, uint32_t k1, int pair_parity,
                            int* __restrict__ accf, int t,
                            const int* __restrict__ nsw) {
  int tid = threadIdx.x;
  if (tid >= NPAIR) return;
  if (t >= *nsw) { accf[tid] = 0; return; }
  int b = tid >> 4;
  float d = (1.0f / T[b] - 1.0f / T[b + 1]) * (Eplane[tid] - Eplane[tid + 16]);
  uint32_t h0, h1;
  tf2x32(k0, k1, 0u, (uint32_t)tid, h0, h1);
  float u = u01(h0 ^ h1);
  float th = (float)exp((double)d);
  accf[tid] = (u < th) && ((b & 1) == pair_parity);
}

// ---- apply accepted swaps: exchange 64KB planes ---------------------------
__global__ __launch_bounds__(256) void pt_swap8_k(uint8_t* __restrict__ s,
                                                  const int* __restrict__ accf) {
  int pc = blockIdx.x;
  if (!accf[pc]) return;
  uint4* p0 = (uint4*)(s + ((size_t)pc << 16));
  uint4* p1 = p0 + (CC * PLANE / 16);
  for (int j = threadIdx.x; j < PLANE / 16; j += 256) {
    uint4 a0 = p0[j], a1 = p1[j];
    p0[j] = a1; p1[j] = a0;
  }
}

// ---- final energies = PT(t=15) permutation of plane energies --------------
__global__ void final_eout_k(const float* __restrict__ Eplane,
                             const int* __restrict__ accf,
                             float* __restrict__ Eout) {
  int tid = threadIdx.x;
  int b = tid >> 4;
  float e = Eplane[tid];
  if (b < 31 && accf[tid])      e = Eplane[tid + 16];
  if (b > 0  && accf[tid - 16]) e = Eplane[tid - 16];
  Eout[tid] = e;
}

// ---- staged in-place int8 -> fp32 expansion (validated R3-R5) -------------
__global__ __launch_bounds__(256) void expand_k(const int8_t* __restrict__ st,
                                                float* __restrict__ out,
                                                int lo, int cnt4) {
  int i = blockIdx.x * 256 + threadIdx.x;
  if (i >= cnt4) return;
  uint32_t v = *(const uint32_t*)(st + lo + 4 * i);
  float4 o;
  o.x = (float)(int8_t)(v);
  o.y = (float)(int8_t)(v >> 8);
  o.z = (float)(int8_t)(v >> 16);
  o.w = (float)(int8_t)(v >> 24);
  ((float4*)out)[(lo >> 2) + i] = o;
}

__global__ __launch_bounds__(256) void expand_head_k(const int8_t* __restrict__ st,
                                                     float* __restrict__ out) {
  uint32_t r[8];
  int t = threadIdx.x;
  for (int u = 0; u < 8; ++u) r[u] = *(const uint32_t*)(st + t * 32 + 4 * u);
  __syncthreads();
  for (int u = 0; u < 8; ++u) {
    uint32_t v = r[u];
    float4 o;
    o.x = (float)(int8_t)(v);
    o.y = (float)(int8_t)(v >> 8);
    o.z = (float)(int8_t)(v >> 16);
    o.w = (float)(int8_t)(v >> 24);
    ((float4*)out)[t * 8 + u] = o;
  }
}

extern "C" void kernel_launch(void* const* d_in, const int* in_sizes, int n_in,
                              void* d_out, int out_size, void* d_ws, size_t ws_size,
                              hipStream_t stream) {
  (void)in_sizes; (void)n_in; (void)out_size; (void)ws_size;
  const float* T    = (const float*)d_in[0];
  const int*  spins = (const int*)d_in[1];
  const int*  nsw   = (const int*)d_in[2];

  uint8_t* buf0 = (uint8_t*)d_out;
  float*   outf = (float*)d_out;
  float*   Eout = outf + NSITE;

  float*    Eplane = (float*)d_ws;               // 512
  uint32_t* M4     = (uint32_t*)(Eplane + 512);  // 32
  uint32_t* M8     = M4 + BB;                    // 32
  int*      accf   = (int*)(M8 + BB);            // 496

  init8_k<<<NSITE / 1024, 256, 0, stream>>>(spins, buf0);
  prep_k<<<1, 64, 0, stream>>>(T, M4, M8);

  for (int g = 0; g < 4; ++g) {
    uint4 kS[4];
    uint32_t k3a = 0, k3b = 0;
    for (int i = 0; i < 4; ++i) {
      int t = 4 * g + i;
      uint32_t kb0, kb1;
      tf2x32(0u, 42u, 0u, (uint32_t)t, kb0, kb1);     // fold_in(key(42), t)
      tf2x32(kb0, kb1, 0u, 0u, kS[i].x, kS[i].y);     // color-0 key
      tf2x32(kb0, kb1, 0u, 1u, kS[i].z, kS[i].w);     // color-1 key
      if (i == 3) tf2x32(kb0, kb1, 0u, 2u, k3a, k3b); // PT key
    }
    sweep4_k<<<BB * CC, 1024, 0, stream>>>(buf0, M4, M8,
                                           kS[0], kS[1], kS[2], kS[3],
                                           4 * g, nsw, Eplane);
    pt_decide_k<<<1, 512, 0, stream>>>(Eplane, T, k3a, k3b, g & 1,
                                       accf, 4 * g + 3, nsw);
    pt_swap8_k<<<NPAIR, 256, 0, stream>>>(buf0, accf);
  }

  final_eout_k<<<1, 512, 0, stream>>>(Eplane, accf, Eout);

  for (int lo = NSITE / 4; lo >= 8192; lo >>= 2) {
    int cnt4 = (lo * 3) / 4;
    expand_k<<<(cnt4 + 255) / 256, 256, 0, stream>>>((int8_t*)buf0, outf, lo, cnt4);
  }
  expand_head_k<<<1, 256, 0, stream>>>((int8_t*)buf0, outf);
}